// Round 1
// 685.244 us; speedup vs baseline: 1.0205x; 1.0205x over previous
//
#include <hip/hip_runtime.h>
#include <hip/hip_bf16.h>
#include <math.h>

typedef unsigned short u16;
typedef __attribute__((ext_vector_type(8))) __bf16 bf16x8;
typedef __attribute__((ext_vector_type(8))) u16 u16x8;
typedef __attribute__((ext_vector_type(4))) u16 u16x4;
typedef __attribute__((ext_vector_type(4))) float fx4;

// B=8, T=1024, D=768, H=12, HD=64, BH=96
__device__ inline u16 f2bf(float f) {
  union { __hip_bfloat16 h; u16 u; } cv;
  cv.h = __float2bfloat16(f);
  return cv.u;
}

// async 16B global -> LDS (wave-uniform LDS base + lane*16)
#define GLDS16(g, l)                                                            \
  __builtin_amdgcn_global_load_lds(                                             \
      (const __attribute__((address_space(1))) void*)(g),                       \
      (__attribute__((address_space(3))) void*)(l), 16, 0, 0)

// ---------------- prep kernels ----------------

// cast x to bf16 AND compute the gate scalar ga1 in the same pass.
// 16 consecutive lanes cover exactly one (b,t,h) 64-float slice.
__global__ void cast_gates_kernel(const float* __restrict__ x, u16* __restrict__ xb,
                                  const float* __restrict__ Wg, const float* __restrict__ bg,
                                  const float* __restrict__ grep_a, float* __restrict__ ga1) {
  __shared__ float wgA[64], wgB[64], bgs[2];
  int tid = threadIdx.x;
  if (tid < 64) {
    const float* wr = Wg + tid * 8;
    wgA[tid] = wr[0] + wr[1] + wr[2] + wr[3];
    wgB[tid] = wr[4] + wr[5] + wr[6] + wr[7];
  }
  if (tid == 0) {
    bgs[0] = bg[0] + bg[1] + bg[2] + bg[3];
    bgs[1] = bg[4] + bg[5] + bg[6] + bg[7];
  }
  __syncthreads();
  size_t i = ((size_t)blockIdx.x * 256 + tid) * 4;
  fx4 v = *(const fx4*)(x + i);
  u16x4 o;
  o[0] = f2bf(v[0]); o[1] = f2bf(v[1]); o[2] = f2bf(v[2]); o[3] = f2bf(v[3]);
  *(u16x4*)(xb + i) = o;

  int d0 = (int)(i & 63);
  float sa = v[0] * wgA[d0] + v[1] * wgA[d0 + 1] + v[2] * wgA[d0 + 2] + v[3] * wgA[d0 + 3];
  float sb = v[0] * wgB[d0] + v[1] * wgB[d0 + 1] + v[2] * wgB[d0 + 2] + v[3] * wgB[d0 + 3];
  #pragma unroll
  for (int m = 1; m < 16; m <<= 1) {
    sa += __shfl_xor(sa, m, 64);
    sb += __shfl_xor(sb, m, 64);
  }
  if ((tid & 15) == 0) {
    size_t e = i;
    int b = (int)(e / 786432);
    int t = (int)((e / 768) & 1023);
    int h = (int)((e >> 6) % 12);
    float saf = sa + bgs[0], sbf = sb + bgs[1];
    float gaV = 1.f / (1.f + __expf(-saf));
    float gbV = 1.f / (1.f + __expf(-sbf));
    ga1[((size_t)(b * 12 + h) << 10) + t] = gaV * (gbV * grep_a[h] - 1.0f) + 2.0f;
  }
}

// coalesced W^T via 64x64 LDS tile ([64][65] f32: 2-way bank pattern = free)
__global__ __launch_bounds__(256) void transpose_w_kernel(
    const float* __restrict__ W0, const float* __restrict__ W1,
    const float* __restrict__ W2, const float* __restrict__ W3,
    u16* __restrict__ T0, u16* __restrict__ T1,
    u16* __restrict__ T2, u16* __restrict__ T3) {
  __shared__ float ls[64][65];
  int z = blockIdx.z;
  const float* W = (z == 0) ? W0 : (z == 1) ? W1 : (z == 2) ? W2 : W3;
  u16* Tp = (z == 0) ? T0 : (z == 1) ? T1 : (z == 2) ? T2 : T3;
  int r0 = blockIdx.y * 64, c0 = blockIdx.x * 64;
  int rowi = threadIdx.x >> 4;
  int col4 = (threadIdx.x & 15) * 4;
  #pragma unroll
  for (int p = 0; p < 4; ++p) {
    int r = p * 16 + rowi;
    fx4 v = *(const fx4*)&W[(size_t)(r0 + r) * 768 + c0 + col4];
    ls[r][col4] = v[0]; ls[r][col4 + 1] = v[1];
    ls[r][col4 + 2] = v[2]; ls[r][col4 + 3] = v[3];
  }
  __syncthreads();
  #pragma unroll
  for (int p = 0; p < 4; ++p) {
    int c = p * 16 + rowi;
    u16x4 o;
    #pragma unroll
    for (int j = 0; j < 4; ++j) o[j] = f2bf(ls[col4 + j][c]);
    *(u16x4*)&Tp[(size_t)(c0 + c) * 768 + r0 + col4] = o;
  }
}

// ---------------- m97-style bf16 MFMA GEMM: 128x128 tile, BK=32, global_load_lds ----------------
// QKV variant: epilogue transposes through LDS for fully-coalesced 16B stores.

__global__ __launch_bounds__(256) void gemm_qkv_kernel(
    const u16* __restrict__ A,
    const u16* __restrict__ Wt0, const u16* __restrict__ Wt1, const u16* __restrict__ Wt2,
    const float* __restrict__ b0, const float* __restrict__ b1, const float* __restrict__ b2,
    u16* __restrict__ outq, u16* __restrict__ outk, u16* __restrict__ outvt) {
  int z = blockIdx.z;
  const u16* Bw = (z == 0) ? Wt0 : (z == 1) ? Wt1 : Wt2;
  const float* bias = (z == 0) ? b0 : (z == 1) ? b1 : b2;
  u16* outp = (z == 0) ? outq : (z == 1) ? outk : outvt;

  __shared__ u16 smem[128 * 132];            // 33792 B; staging aliases the front
  u16* As = smem;                            // [128][32] unpadded (global_load_lds layout)
  u16* Bs = smem + 128 * 32;                 // [128][32]

  int tid = threadIdx.x;
  int w = tid >> 6, lane = tid & 63;
  int ln = lane & 15, quad = lane >> 4;
  int wm = w >> 1, wn = w & 1;
  int m0 = blockIdx.y * 128, n0 = blockIdx.x * 128;
  int srow = w * 16 + (lane >> 2);           // staging row within 64-row half
  int scol = (lane & 3) * 8;                 // staging col (u16 elems)

  fx4 acc[4][4];
  #pragma unroll
  for (int i = 0; i < 4; ++i)
    #pragma unroll
    for (int j = 0; j < 4; ++j) acc[i][j] = (fx4){0.f, 0.f, 0.f, 0.f};

  for (int kk = 0; kk < 768; kk += 32) {
    __syncthreads();
    #pragma unroll
    for (int p = 0; p < 2; ++p) {
      int r = p * 64 + srow;
      GLDS16(A  + (size_t)(m0 + r) * 768 + kk + scol, As + (p * 64 + w * 16) * 32);
      GLDS16(Bw + (size_t)(n0 + r) * 768 + kk + scol, Bs + (p * 64 + w * 16) * 32);
    }
    __syncthreads();
    bf16x8 af[4], bfv[4];
    #pragma unroll
    for (int mt = 0; mt < 4; ++mt) af[mt]  = *(const bf16x8*)&As[(wm * 64 + mt * 16 + ln) * 32 + quad * 8];
    #pragma unroll
    for (int nt = 0; nt < 4; ++nt) bfv[nt] = *(const bf16x8*)&Bs[(wn * 64 + nt * 16 + ln) * 32 + quad * 8];
    #pragma unroll
    for (int mt = 0; mt < 4; ++mt)
      #pragma unroll
      for (int nt = 0; nt < 4; ++nt)
        acc[mt][nt] = __builtin_amdgcn_mfma_f32_16x16x32_bf16(af[mt], bfv[nt], acc[mt][nt], 0, 0, 0);
  }

  // ---- epilogue: C tile -> LDS (stride 132) -> coalesced 16B stores ----
  __syncthreads();
  #pragma unroll
  for (int mt = 0; mt < 4; ++mt) {
    #pragma unroll
    for (int nt = 0; nt < 4; ++nt) {
      int nn = wn * 64 + nt * 16 + ln;
      float bv = bias[n0 + nn];
      #pragma unroll
      for (int r = 0; r < 4; ++r) {
        int mm = wm * 64 + mt * 16 + quad * 4 + r;
        u16 val = f2bf(acc[mt][nt][r] + bv);
        if (z < 2) smem[mm * 132 + nn] = val;   // [m][n]
        else       smem[nn * 132 + mm] = val;   // [n][m]
      }
    }
  }
  __syncthreads();
  int b = m0 >> 10;
  #pragma unroll
  for (int p = 0; p < 4; ++p) {
    int row = p * 32 + (tid >> 3);
    #pragma unroll
    for (int c = 0; c < 2; ++c) {
      int col = c * 64 + (tid & 7) * 8;
      u16x8 v = *(const u16x8*)&smem[row * 132 + col];
      if (z < 2) {
        int ng = n0 + col; int h = ng >> 6, hd = ng & 63;
        int t = (m0 + row) & 1023;
        *(u16x8*)&outp[((size_t)(b * 12 + h) * 1024 + t) * 64 + hd] = v;
      } else {
        int ng = n0 + row; int h = ng >> 6, hd = ng & 63;
        int t = (m0 + col) & 1023;
        *(u16x8*)&outp[((size_t)(b * 12 + h) * 64 + hd) * 1024 + t] = v;
      }
    }
  }
}

// output GEMM: fp32 epilogue is already line-coalesced (16 lanes x 4B = 64B)
__global__ __launch_bounds__(256) void gemm_out_kernel(
    const u16* __restrict__ A, const u16* __restrict__ Bw,
    const float* __restrict__ bias, float* __restrict__ outf) {
  __shared__ u16 As[128 * 32];
  __shared__ u16 Bs[128 * 32];
  int tid = threadIdx.x;
  int w = tid >> 6, lane = tid & 63;
  int ln = lane & 15, quad = lane >> 4;
  int wm = w >> 1, wn = w & 1;
  int m0 = blockIdx.y * 128, n0 = blockIdx.x * 128;
  int srow = w * 16 + (lane >> 2);
  int scol = (lane & 3) * 8;
  fx4 acc[4][4];
  #pragma unroll
  for (int i = 0; i < 4; ++i)
    #pragma unroll
    for (int j = 0; j < 4; ++j) acc[i][j] = (fx4){0.f, 0.f, 0.f, 0.f};

  for (int kk = 0; kk < 768; kk += 32) {
    __syncthreads();
    #pragma unroll
    for (int p = 0; p < 2; ++p) {
      int r = p * 64 + srow;
      GLDS16(A  + (size_t)(m0 + r) * 768 + kk + scol, As + (p * 64 + w * 16) * 32);
      GLDS16(Bw + (size_t)(n0 + r) * 768 + kk + scol, Bs + (p * 64 + w * 16) * 32);
    }
    __syncthreads();
    bf16x8 af[4], bfv[4];
    #pragma unroll
    for (int mt = 0; mt < 4; ++mt) af[mt]  = *(const bf16x8*)&As[(wm * 64 + mt * 16 + ln) * 32 + quad * 8];
    #pragma unroll
    for (int nt = 0; nt < 4; ++nt) bfv[nt] = *(const bf16x8*)&Bs[(wn * 64 + nt * 16 + ln) * 32 + quad * 8];
    #pragma unroll
    for (int mt = 0; mt < 4; ++mt)
      #pragma unroll
      for (int nt = 0; nt < 4; ++nt)
        acc[mt][nt] = __builtin_amdgcn_mfma_f32_16x16x32_bf16(af[mt], bfv[nt], acc[mt][nt], 0, 0, 0);
  }
  #pragma unroll
  for (int mt = 0; mt < 4; ++mt) {
    int mg0 = m0 + wm * 64 + mt * 16 + quad * 4;
    #pragma unroll
    for (int nt = 0; nt < 4; ++nt) {
      int ng = n0 + wn * 64 + nt * 16 + ln;
      float bv = bias[ng];
      #pragma unroll
      for (int r = 0; r < 4; ++r)
        outf[(size_t)(mg0 + r) * 768 + ng] = acc[mt][nt][r] + bv;
    }
  }
}

// ---------------- flash attention with gated transposed rel_bias ----------------
// T14 pipeline: prefetch kt+1's K/V tile into regs + kt+1's rel_bias/mask into regs
// at the top of iteration kt; regs->LDS write lands after the post-compute barrier.

__global__ __launch_bounds__(256) void attn_kernel(
    const u16* __restrict__ qb, const u16* __restrict__ kb, const u16* __restrict__ vtb,
    const float* __restrict__ rel_bias, const float* __restrict__ amask,
    const float* __restrict__ ga1, u16* __restrict__ attn_out) {
  __shared__ u16 Ks[64][72];
  __shared__ u16 Vs[64][72];
  __shared__ u16 Ps[4][16][72];
  int g = blockIdx.x;
  int xcd = g & 7;
  int idx = g >> 3;
  int bh = xcd * 12 + (idx % 12);
  int qt = idx / 12;
  int b = bh / 12, h = bh % 12;
  int tid = threadIdx.x;
  int w = tid >> 6, lane = tid & 63;
  int ln = lane & 15, quad = lane >> 4;
  int q0 = qt * 64 + w * 16;

  const u16* qrow = qb + ((size_t)bh * 1024 + q0 + ln) * 64 + quad * 8;
  bf16x8 qf0 = *(const bf16x8*)qrow;
  bf16x8 qf1 = *(const bf16x8*)(qrow + 32);
  fx4 ga = *(const fx4*)(ga1 + (size_t)bh * 1024 + q0 + quad * 4);
  const float* rb_base = rel_bias + (size_t)bh * 1024 * 1024 + q0 + quad * 4;
  const float* am_base = amask + b * 1024;

  int srow = tid >> 3;                 // staging row (0..31 for p=0, +32 for p=1)
  int sc8 = (tid & 7) * 8;             // staging col (u16 elems)

  fx4 o[4];
  #pragma unroll
  for (int i = 0; i < 4; ++i) o[i] = (fx4){0.f, 0.f, 0.f, 0.f};
  float m_run[4] = {-1e30f, -1e30f, -1e30f, -1e30f};
  float l_run[4] = {0.f, 0.f, 0.f, 0.f};
  const float scaling = 0.125f;

  // ---- prologue: tile 0 ----
  u16x8 kreg[2], vreg[2];
  #pragma unroll
  for (int p = 0; p < 2; ++p) {
    int row = p * 32 + srow;
    kreg[p] = *(const u16x8*)&kb[((size_t)bh * 1024 + row) * 64 + sc8];
    vreg[p] = *(const u16x8*)&vtb[((size_t)bh * 64 + row) * 1024 + sc8];
  }
  fx4 rbc[4]; float mkc[4];
  #pragma unroll
  for (int kf = 0; kf < 4; ++kf) {
    int key = kf * 16 + ln;
    mkc[kf] = am_base[key];
    rbc[kf] = *(const fx4*)(rb_base + (size_t)key * 1024);
  }
  #pragma unroll
  for (int p = 0; p < 2; ++p) {
    int row = p * 32 + srow;
    *(u16x8*)&Ks[row][sc8] = kreg[p];
    *(u16x8*)&Vs[row][sc8] = vreg[p];
  }
  __syncthreads();

  for (int kt = 0; kt < 16; ++kt) {
    // ---- issue prefetch for kt+1 (overlaps the whole compute phase) ----
    fx4 rbn[4]; float mkn[4];
    if (kt < 15) {
      int k0n = (kt + 1) * 64;
      #pragma unroll
      for (int p = 0; p < 2; ++p) {
        int row = p * 32 + srow;
        kreg[p] = *(const u16x8*)&kb[((size_t)bh * 1024 + k0n + row) * 64 + sc8];
        vreg[p] = *(const u16x8*)&vtb[((size_t)bh * 64 + row) * 1024 + k0n + sc8];
      }
      #pragma unroll
      for (int kf = 0; kf < 4; ++kf) {
        int key = k0n + kf * 16 + ln;
        mkn[kf] = am_base[key];
        rbn[kf] = *(const fx4*)(rb_base + (size_t)key * 1024);
      }
    }

    // ---- QK^T ----
    fx4 s[4];
    __builtin_amdgcn_s_setprio(1);
    #pragma unroll
    for (int kf = 0; kf < 4; ++kf) {
      fx4 a2 = (fx4){0.f, 0.f, 0.f, 0.f};
      bf16x8 kb0 = *(const bf16x8*)&Ks[kf * 16 + ln][quad * 8];
      bf16x8 kb1 = *(const bf16x8*)&Ks[kf * 16 + ln][32 + quad * 8];
      a2 = __builtin_amdgcn_mfma_f32_16x16x32_bf16(qf0, kb0, a2, 0, 0, 0);
      a2 = __builtin_amdgcn_mfma_f32_16x16x32_bf16(qf1, kb1, a2, 0, 0, 0);
      s[kf] = a2;
    }
    __builtin_amdgcn_s_setprio(0);

    // ---- softmax (online) ----
    float mt4[4] = {-1e30f, -1e30f, -1e30f, -1e30f};
    #pragma unroll
    for (int kf = 0; kf < 4; ++kf) {
      #pragma unroll
      for (int r = 0; r < 4; ++r) {
        float sv = s[kf][r] * scaling + ga[r] * rbc[kf][r] + mkc[kf];
        s[kf][r] = sv;
        mt4[r] = fmaxf(mt4[r], sv);
      }
    }
    #pragma unroll
    for (int mask = 1; mask < 16; mask <<= 1)
      #pragma unroll
      for (int r = 0; r < 4; ++r)
        mt4[r] = fmaxf(mt4[r], __shfl_xor(mt4[r], mask, 64));

    float alpha[4], rs[4];
    #pragma unroll
    for (int r = 0; r < 4; ++r) {
      float mn = fmaxf(m_run[r], mt4[r]);
      alpha[r] = __expf(m_run[r] - mn);
      m_run[r] = mn;
      rs[r] = 0.f;
    }
    #pragma unroll
    for (int kf = 0; kf < 4; ++kf)
      #pragma unroll
      for (int r = 0; r < 4; ++r) {
        float p = __expf(s[kf][r] - m_run[r]);
        s[kf][r] = p;
        rs[r] += p;
      }
    #pragma unroll
    for (int mask = 1; mask < 16; mask <<= 1)
      #pragma unroll
      for (int r = 0; r < 4; ++r)
        rs[r] += __shfl_xor(rs[r], mask, 64);
    #pragma unroll
    for (int r = 0; r < 4; ++r)
      l_run[r] = l_run[r] * alpha[r] + rs[r];

    #pragma unroll
    for (int kf = 0; kf < 4; ++kf)
      #pragma unroll
      for (int r = 0; r < 4; ++r)
        Ps[w][quad * 4 + r][kf * 16 + ln] = f2bf(s[kf][r]);
    #pragma unroll
    for (int df = 0; df < 4; ++df)
      #pragma unroll
      for (int r = 0; r < 4; ++r)
        o[df][r] *= alpha[r];

    // ---- P·V ----
    bf16x8 pa0 = *(const bf16x8*)&Ps[w][ln][quad * 8];
    bf16x8 pa1 = *(const bf16x8*)&Ps[w][ln][32 + quad * 8];
    __builtin_amdgcn_s_setprio(1);
    #pragma unroll
    for (int df = 0; df < 4; ++df) {
      bf16x8 vv0 = *(const bf16x8*)&Vs[df * 16 + ln][quad * 8];
      bf16x8 vv1 = *(const bf16x8*)&Vs[df * 16 + ln][32 + quad * 8];
      o[df] = __builtin_amdgcn_mfma_f32_16x16x32_bf16(pa0, vv0, o[df], 0, 0, 0);
      o[df] = __builtin_amdgcn_mfma_f32_16x16x32_bf16(pa1, vv1, o[df], 0, 0, 0);
    }
    __builtin_amdgcn_s_setprio(0);

    // ---- write-late: land prefetched tile, rotate rb regs ----
    if (kt < 15) {
      __syncthreads();                 // all warps done reading Ks/Vs of tile kt
      #pragma unroll
      for (int p = 0; p < 2; ++p) {
        int row = p * 32 + srow;
        *(u16x8*)&Ks[row][sc8] = kreg[p];
        *(u16x8*)&Vs[row][sc8] = vreg[p];
      }
      #pragma unroll
      for (int kf = 0; kf < 4; ++kf) { rbc[kf] = rbn[kf]; mkc[kf] = mkn[kf]; }
      __syncthreads();                 // tile kt+1 visible
    }
  }

  float inv[4];
  #pragma unroll
  for (int r = 0; r < 4; ++r) inv[r] = 1.0f / l_run[r];
  #pragma unroll
  for (int df = 0; df < 4; ++df)
    #pragma unroll
    for (int r = 0; r < 4; ++r) {
      int qg = q0 + quad * 4 + r;
      float val = o[df][r] * inv[r];
      attn_out[((size_t)b * 1024 + qg) * 768 + h * 64 + df * 16 + ln] = f2bf(val);
    }
}

// ---------------- launch ----------------

extern "C" void kernel_launch(void* const* d_in, const int* in_sizes, int n_in,
                              void* d_out, int out_size, void* d_ws, size_t ws_size,
                              hipStream_t stream) {
  const float* x         = (const float*)d_in[0];
  const float* attn_mask = (const float*)d_in[1];
  const float* rel_bias  = (const float*)d_in[2];
  const float* Wq        = (const float*)d_in[3];
  const float* bq        = (const float*)d_in[4];
  const float* Wk        = (const float*)d_in[5];
  const float* bk        = (const float*)d_in[6];
  const float* Wv        = (const float*)d_in[7];
  const float* bv        = (const float*)d_in[8];
  const float* Wo        = (const float*)d_in[9];
  const float* bo        = (const float*)d_in[10];
  const float* Wg        = (const float*)d_in[11];
  const float* bg        = (const float*)d_in[12];
  const float* grep_a    = (const float*)d_in[13];

  char* ws = (char*)d_ws;
  const size_t SZ_XD = (size_t)8192 * 768 * 2;
  const size_t SZ_W  = (size_t)768 * 768 * 2;
  u16*   xb   = (u16*)(ws);
  u16*   wqt  = (u16*)(ws + SZ_XD);
  u16*   wkt  = (u16*)(ws + SZ_XD + SZ_W);
  u16*   wvt  = (u16*)(ws + SZ_XD + 2 * SZ_W);
  u16*   wot  = (u16*)(ws + SZ_XD + 3 * SZ_W);
  u16*   qbuf = (u16*)(ws + SZ_XD + 4 * SZ_W);
  u16*   kbuf = (u16*)(ws + 2 * SZ_XD + 4 * SZ_W);
  u16*   vtbuf= (u16*)(ws + 3 * SZ_XD + 4 * SZ_W);
  u16*   attnb= (u16*)(ws + 4 * SZ_XD + 4 * SZ_W);
  float* ga1f = (float*)(ws + 5 * SZ_XD + 4 * SZ_W);

  cast_gates_kernel<<<6144, 256, 0, stream>>>(x, xb, Wg, bg, grep_a, ga1f);
  transpose_w_kernel<<<dim3(12, 12, 4), 256, 0, stream>>>(Wq, Wk, Wv, Wo, wqt, wkt, wvt, wot);
  gemm_qkv_kernel<<<dim3(6, 64, 3), 256, 0, stream>>>(xb, wqt, wkt, wvt, bq, bk, bv,
                                                      qbuf, kbuf, vtbuf);
  attn_kernel<<<1536, 256, 0, stream>>>(qbuf, kbuf, vtbuf, rel_bias, attn_mask, ga1f, attnb);
  gemm_out_kernel<<<dim3(6, 64), 256, 0, stream>>>(attnb, wot, bo, (float*)d_out);
}

// Round 2
// 681.226 us; speedup vs baseline: 1.0265x; 1.0059x over previous
//
#include <hip/hip_runtime.h>
#include <hip/hip_bf16.h>
#include <math.h>

typedef unsigned short u16;
typedef __attribute__((ext_vector_type(8))) __bf16 bf16x8;
typedef __attribute__((ext_vector_type(8))) u16 u16x8;
typedef __attribute__((ext_vector_type(4))) u16 u16x4;
typedef __attribute__((ext_vector_type(4))) float fx4;

// B=8, T=1024, D=768, H=12, HD=64, BH=96
__device__ inline u16 f2bf(float f) {
  union { __hip_bfloat16 h; u16 u; } cv;
  cv.h = __float2bfloat16(f);
  return cv.u;
}

// async 16B global -> LDS (wave-uniform LDS base + lane*16)
#define GLDS16(g, l)                                                            \
  __builtin_amdgcn_global_load_lds(                                             \
      (const __attribute__((address_space(1))) void*)(g),                       \
      (__attribute__((address_space(3))) void*)(l), 16, 0, 0)

// ---------------- prep kernels ----------------

// cast x to bf16 AND compute the gate scalar ga1 in the same pass.
// 16 consecutive lanes cover exactly one (b,t,h) 64-float slice.
__global__ void cast_gates_kernel(const float* __restrict__ x, u16* __restrict__ xb,
                                  const float* __restrict__ Wg, const float* __restrict__ bg,
                                  const float* __restrict__ grep_a, float* __restrict__ ga1) {
  __shared__ float wgA[64], wgB[64], bgs[2];
  int tid = threadIdx.x;
  if (tid < 64) {
    const float* wr = Wg + tid * 8;
    wgA[tid] = wr[0] + wr[1] + wr[2] + wr[3];
    wgB[tid] = wr[4] + wr[5] + wr[6] + wr[7];
  }
  if (tid == 0) {
    bgs[0] = bg[0] + bg[1] + bg[2] + bg[3];
    bgs[1] = bg[4] + bg[5] + bg[6] + bg[7];
  }
  __syncthreads();
  size_t i = ((size_t)blockIdx.x * 256 + tid) * 4;
  fx4 v = *(const fx4*)(x + i);
  u16x4 o;
  o[0] = f2bf(v[0]); o[1] = f2bf(v[1]); o[2] = f2bf(v[2]); o[3] = f2bf(v[3]);
  *(u16x4*)(xb + i) = o;

  int d0 = (int)(i & 63);
  float sa = v[0] * wgA[d0] + v[1] * wgA[d0 + 1] + v[2] * wgA[d0 + 2] + v[3] * wgA[d0 + 3];
  float sb = v[0] * wgB[d0] + v[1] * wgB[d0 + 1] + v[2] * wgB[d0 + 2] + v[3] * wgB[d0 + 3];
  #pragma unroll
  for (int m = 1; m < 16; m <<= 1) {
    sa += __shfl_xor(sa, m, 64);
    sb += __shfl_xor(sb, m, 64);
  }
  if ((tid & 15) == 0) {
    size_t e = i;
    int b = (int)(e / 786432);
    int t = (int)((e / 768) & 1023);
    int h = (int)((e >> 6) % 12);
    float saf = sa + bgs[0], sbf = sb + bgs[1];
    float gaV = 1.f / (1.f + __expf(-saf));
    float gbV = 1.f / (1.f + __expf(-sbf));
    ga1[((size_t)(b * 12 + h) << 10) + t] = gaV * (gbV * grep_a[h] - 1.0f) + 2.0f;
  }
}

// coalesced W^T via 64x64 LDS tile ([64][65] f32: 2-way bank pattern = free)
__global__ __launch_bounds__(256) void transpose_w_kernel(
    const float* __restrict__ W0, const float* __restrict__ W1,
    const float* __restrict__ W2, const float* __restrict__ W3,
    u16* __restrict__ T0, u16* __restrict__ T1,
    u16* __restrict__ T2, u16* __restrict__ T3) {
  __shared__ float ls[64][65];
  int z = blockIdx.z;
  const float* W = (z == 0) ? W0 : (z == 1) ? W1 : (z == 2) ? W2 : W3;
  u16* Tp = (z == 0) ? T0 : (z == 1) ? T1 : (z == 2) ? T2 : T3;
  int r0 = blockIdx.y * 64, c0 = blockIdx.x * 64;
  int rowi = threadIdx.x >> 4;
  int col4 = (threadIdx.x & 15) * 4;
  #pragma unroll
  for (int p = 0; p < 4; ++p) {
    int r = p * 16 + rowi;
    fx4 v = *(const fx4*)&W[(size_t)(r0 + r) * 768 + c0 + col4];
    ls[r][col4] = v[0]; ls[r][col4 + 1] = v[1];
    ls[r][col4 + 2] = v[2]; ls[r][col4 + 3] = v[3];
  }
  __syncthreads();
  #pragma unroll
  for (int p = 0; p < 4; ++p) {
    int c = p * 16 + rowi;
    u16x4 o;
    #pragma unroll
    for (int j = 0; j < 4; ++j) o[j] = f2bf(ls[col4 + j][c]);
    *(u16x4*)&Tp[(size_t)(c0 + c) * 768 + r0 + col4] = o;
  }
}

// ---------------- m97-style bf16 MFMA GEMM: 128x128 tile, BK=32, global_load_lds ----------------
// QKV variant: epilogue transposes through LDS for fully-coalesced 16B stores.

__global__ __launch_bounds__(256) void gemm_qkv_kernel(
    const u16* __restrict__ A,
    const u16* __restrict__ Wt0, const u16* __restrict__ Wt1, const u16* __restrict__ Wt2,
    const float* __restrict__ b0, const float* __restrict__ b1, const float* __restrict__ b2,
    u16* __restrict__ outq, u16* __restrict__ outk, u16* __restrict__ outvt) {
  int z = blockIdx.z;
  const u16* Bw = (z == 0) ? Wt0 : (z == 1) ? Wt1 : Wt2;
  const float* bias = (z == 0) ? b0 : (z == 1) ? b1 : b2;
  u16* outp = (z == 0) ? outq : (z == 1) ? outk : outvt;

  __shared__ u16 smem[128 * 132];            // 33792 B; staging aliases the front
  u16* As = smem;                            // [128][32] unpadded (global_load_lds layout)
  u16* Bs = smem + 128 * 32;                 // [128][32]

  int tid = threadIdx.x;
  int w = tid >> 6, lane = tid & 63;
  int ln = lane & 15, quad = lane >> 4;
  int wm = w >> 1, wn = w & 1;
  int m0 = blockIdx.y * 128, n0 = blockIdx.x * 128;
  int srow = w * 16 + (lane >> 2);           // staging row within 64-row half
  int scol = (lane & 3) * 8;                 // staging col (u16 elems)

  fx4 acc[4][4];
  #pragma unroll
  for (int i = 0; i < 4; ++i)
    #pragma unroll
    for (int j = 0; j < 4; ++j) acc[i][j] = (fx4){0.f, 0.f, 0.f, 0.f};

  for (int kk = 0; kk < 768; kk += 32) {
    __syncthreads();
    #pragma unroll
    for (int p = 0; p < 2; ++p) {
      int r = p * 64 + srow;
      GLDS16(A  + (size_t)(m0 + r) * 768 + kk + scol, As + (p * 64 + w * 16) * 32);
      GLDS16(Bw + (size_t)(n0 + r) * 768 + kk + scol, Bs + (p * 64 + w * 16) * 32);
    }
    __syncthreads();
    bf16x8 af[4], bfv[4];
    #pragma unroll
    for (int mt = 0; mt < 4; ++mt) af[mt]  = *(const bf16x8*)&As[(wm * 64 + mt * 16 + ln) * 32 + quad * 8];
    #pragma unroll
    for (int nt = 0; nt < 4; ++nt) bfv[nt] = *(const bf16x8*)&Bs[(wn * 64 + nt * 16 + ln) * 32 + quad * 8];
    #pragma unroll
    for (int mt = 0; mt < 4; ++mt)
      #pragma unroll
      for (int nt = 0; nt < 4; ++nt)
        acc[mt][nt] = __builtin_amdgcn_mfma_f32_16x16x32_bf16(af[mt], bfv[nt], acc[mt][nt], 0, 0, 0);
  }

  // ---- epilogue: C tile -> LDS (stride 132) -> coalesced 16B stores ----
  __syncthreads();
  #pragma unroll
  for (int mt = 0; mt < 4; ++mt) {
    #pragma unroll
    for (int nt = 0; nt < 4; ++nt) {
      int nn = wn * 64 + nt * 16 + ln;
      float bv = bias[n0 + nn];
      #pragma unroll
      for (int r = 0; r < 4; ++r) {
        int mm = wm * 64 + mt * 16 + quad * 4 + r;
        u16 val = f2bf(acc[mt][nt][r] + bv);
        if (z < 2) smem[mm * 132 + nn] = val;   // [m][n]
        else       smem[nn * 132 + mm] = val;   // [n][m]
      }
    }
  }
  __syncthreads();
  int b = m0 >> 10;
  #pragma unroll
  for (int p = 0; p < 4; ++p) {
    int row = p * 32 + (tid >> 3);
    #pragma unroll
    for (int c = 0; c < 2; ++c) {
      int col = c * 64 + (tid & 7) * 8;
      u16x8 v = *(const u16x8*)&smem[row * 132 + col];
      if (z < 2) {
        int ng = n0 + col; int h = ng >> 6, hd = ng & 63;
        int t = (m0 + row) & 1023;
        *(u16x8*)&outp[((size_t)(b * 12 + h) * 1024 + t) * 64 + hd] = v;
      } else {
        int ng = n0 + row; int h = ng >> 6, hd = ng & 63;
        int t = (m0 + col) & 1023;
        *(u16x8*)&outp[((size_t)(b * 12 + h) * 64 + hd) * 1024 + t] = v;
      }
    }
  }
}

// output GEMM: fp32 epilogue is already line-coalesced (16 lanes x 4B = 64B)
__global__ __launch_bounds__(256) void gemm_out_kernel(
    const u16* __restrict__ A, const u16* __restrict__ Bw,
    const float* __restrict__ bias, float* __restrict__ outf) {
  __shared__ u16 As[128 * 32];
  __shared__ u16 Bs[128 * 32];
  int tid = threadIdx.x;
  int w = tid >> 6, lane = tid & 63;
  int ln = lane & 15, quad = lane >> 4;
  int wm = w >> 1, wn = w & 1;
  int m0 = blockIdx.y * 128, n0 = blockIdx.x * 128;
  int srow = w * 16 + (lane >> 2);
  int scol = (lane & 3) * 8;
  fx4 acc[4][4];
  #pragma unroll
  for (int i = 0; i < 4; ++i)
    #pragma unroll
    for (int j = 0; j < 4; ++j) acc[i][j] = (fx4){0.f, 0.f, 0.f, 0.f};

  for (int kk = 0; kk < 768; kk += 32) {
    __syncthreads();
    #pragma unroll
    for (int p = 0; p < 2; ++p) {
      int r = p * 64 + srow;
      GLDS16(A  + (size_t)(m0 + r) * 768 + kk + scol, As + (p * 64 + w * 16) * 32);
      GLDS16(Bw + (size_t)(n0 + r) * 768 + kk + scol, Bs + (p * 64 + w * 16) * 32);
    }
    __syncthreads();
    bf16x8 af[4], bfv[4];
    #pragma unroll
    for (int mt = 0; mt < 4; ++mt) af[mt]  = *(const bf16x8*)&As[(wm * 64 + mt * 16 + ln) * 32 + quad * 8];
    #pragma unroll
    for (int nt = 0; nt < 4; ++nt) bfv[nt] = *(const bf16x8*)&Bs[(wn * 64 + nt * 16 + ln) * 32 + quad * 8];
    #pragma unroll
    for (int mt = 0; mt < 4; ++mt)
      #pragma unroll
      for (int nt = 0; nt < 4; ++nt)
        acc[mt][nt] = __builtin_amdgcn_mfma_f32_16x16x32_bf16(af[mt], bfv[nt], acc[mt][nt], 0, 0, 0);
  }
  #pragma unroll
  for (int mt = 0; mt < 4; ++mt) {
    int mg0 = m0 + wm * 64 + mt * 16 + quad * 4;
    #pragma unroll
    for (int nt = 0; nt < 4; ++nt) {
      int ng = n0 + wn * 64 + nt * 16 + ln;
      float bv = bias[ng];
      #pragma unroll
      for (int r = 0; r < 4; ++r)
        outf[(size_t)(mg0 + r) * 768 + ng] = acc[mt][nt][r] + bv;
    }
  }
}

// ---------------- flash attention v2: MT=2 (32 q/wave), GLDS-double-buffered K/V,
// one barrier per tile, XOR-swizzled K/V LDS, mid-iteration rb prefetch ----------------

// stage one 64x64 u16 K tile and V tile into KV[buf] via global_load_lds.
// LDS is linear per row (128 B); global source column is inverse-swizzled so that
// LDS[row][c] holds global[row][c ^ ((row&7)<<4)]  (Guideline 21).
#define STAGE_KV(buf_, k0_)                                                     \
  {                                                                             \
    _Pragma("unroll")                                                           \
    for (int p = 0; p < 2; ++p) {                                               \
      int ch = w * 2 + p;                                                       \
      int row = ch * 8 + (lane >> 3);                                           \
      GLDS16(kb  + ((size_t)bh * 1024 + (k0_) + row) * 64 + (csw16 >> 1),       \
             &KV[buf_][0][ch * 512]);                                           \
      GLDS16(vtb + ((size_t)bh * 64 + row) * 1024 + (k0_) + (csw16 >> 1),       \
             &KV[buf_][1][ch * 512]);                                           \
    }                                                                           \
  }

__global__ __launch_bounds__(256) void attn_kernel(
    const u16* __restrict__ qb, const u16* __restrict__ kb, const u16* __restrict__ vtb,
    const float* __restrict__ rel_bias, const float* __restrict__ amask,
    const float* __restrict__ ga1, u16* __restrict__ attn_out) {
  __shared__ u16 KV[2][2][64 * 64];     // [buf][K|V][row*64], rows 128 B, swizzled
  __shared__ u16 Ps[4][32][72];         // per-warp P / output staging
  int g = blockIdx.x;                   // 768 = 8 xcd * 96
  int xcd = g & 7;
  int idx = g >> 3;                     // 0..95
  int bh = xcd * 12 + (idx % 12);
  int qt = idx / 12;                    // 0..7
  int b = bh / 12, h = bh % 12;
  int tid = threadIdx.x;
  int w = tid >> 6, lane = tid & 63;
  int ln = lane & 15, quad = lane >> 4;
  int q0 = qt * 128 + w * 32;

  // swizzled staging source column (bytes); row&7 == lane>>3 for all chunks
  int csw16 = (((lane & 7) ^ (lane >> 3)) << 4);
  // swizzle mask for fragment reads: row&7 == ln&7 for all kf/df
  int swl = (ln & 7) << 4;
  int c0 = (quad * 16) ^ swl;           // byte offset of d/k chunk 0
  int c1 = (64 + quad * 16) ^ swl;      // byte offset of d/k chunk 1

  bf16x8 qf[2][2];
  fx4 ga[2];
  #pragma unroll
  for (int mt = 0; mt < 2; ++mt) {
    const u16* qrow = qb + ((size_t)bh * 1024 + q0 + mt * 16 + ln) * 64 + quad * 8;
    qf[mt][0] = *(const bf16x8*)qrow;
    qf[mt][1] = *(const bf16x8*)(qrow + 32);
    ga[mt] = *(const fx4*)(ga1 + (size_t)bh * 1024 + q0 + mt * 16 + quad * 4);
  }
  const float* rb_base = rel_bias + (size_t)bh * 1024 * 1024 + q0 + quad * 4;
  const float* am_base = amask + b * 1024;

  fx4 o[2][4];
  float m_run[2][4], l_run[2][4];
  #pragma unroll
  for (int mt = 0; mt < 2; ++mt)
    #pragma unroll
    for (int i = 0; i < 4; ++i) {
      o[mt][i] = (fx4){0.f, 0.f, 0.f, 0.f};
      m_run[mt][i] = -1e30f;
      l_run[mt][i] = 0.f;
    }
  const float scaling = 0.125f;

  // prologue: stage tile 0, load rb/mask for tile 0
  STAGE_KV(0, 0);
  fx4 rbc[2][4];
  float mkc[4];
  #pragma unroll
  for (int kf = 0; kf < 4; ++kf) {
    int key = kf * 16 + ln;
    mkc[kf] = am_base[key];
    #pragma unroll
    for (int mt = 0; mt < 2; ++mt)
      rbc[mt][kf] = *(const fx4*)(rb_base + (size_t)key * 1024 + mt * 16);
  }

  for (int kt = 0; kt < 16; ++kt) {
    int cur = kt & 1;
    __syncthreads();                       // tile kt visible; prev buffer reads done
    if (kt < 15) STAGE_KV(cur ^ 1, (kt + 1) * 64);   // full-iteration cover
    const char* Kb = (const char*)&KV[cur][0][0];
    const char* Vb = (const char*)&KV[cur][1][0];

    // ---- QK^T (16 MFMA; K-frags shared across mt) ----
    fx4 s[2][4];
    __builtin_amdgcn_s_setprio(1);
    #pragma unroll
    for (int kf = 0; kf < 4; ++kf) {
      int krow = kf * 16 + ln;
      bf16x8 kb0 = *(const bf16x8*)(Kb + krow * 128 + c0);
      bf16x8 kb1 = *(const bf16x8*)(Kb + krow * 128 + c1);
      #pragma unroll
      for (int mt = 0; mt < 2; ++mt) {
        fx4 a2 = (fx4){0.f, 0.f, 0.f, 0.f};
        a2 = __builtin_amdgcn_mfma_f32_16x16x32_bf16(qf[mt][0], kb0, a2, 0, 0, 0);
        a2 = __builtin_amdgcn_mfma_f32_16x16x32_bf16(qf[mt][1], kb1, a2, 0, 0, 0);
        s[mt][kf] = a2;
      }
    }
    __builtin_amdgcn_s_setprio(0);

    // ---- fold scale/gate/bias/mask (last use of rbc/mkc) ----
    float mt4[2][4];
    #pragma unroll
    for (int mt = 0; mt < 2; ++mt)
      #pragma unroll
      for (int r = 0; r < 4; ++r) mt4[mt][r] = -1e30f;
    #pragma unroll
    for (int kf = 0; kf < 4; ++kf)
      #pragma unroll
      for (int mt = 0; mt < 2; ++mt)
        #pragma unroll
        for (int r = 0; r < 4; ++r) {
          float sv = s[mt][kf][r] * scaling + ga[mt][r] * rbc[mt][kf][r] + mkc[kf];
          s[mt][kf][r] = sv;
          mt4[mt][r] = fmaxf(mt4[mt][r], sv);
        }

    // ---- prefetch rb/mask for tile kt+1 (covers softmax+PV+next QK) ----
    if (kt < 15) {
      int k0n = (kt + 1) * 64;
      #pragma unroll
      for (int kf = 0; kf < 4; ++kf) {
        int key = k0n + kf * 16 + ln;
        mkc[kf] = am_base[key];
        #pragma unroll
        for (int mt = 0; mt < 2; ++mt)
          rbc[mt][kf] = *(const fx4*)(rb_base + (size_t)key * 1024 + mt * 16);
      }
    }

    // ---- online softmax ----
    #pragma unroll
    for (int mask = 1; mask < 16; mask <<= 1)
      #pragma unroll
      for (int mt = 0; mt < 2; ++mt)
        #pragma unroll
        for (int r = 0; r < 4; ++r)
          mt4[mt][r] = fmaxf(mt4[mt][r], __shfl_xor(mt4[mt][r], mask, 64));

    float alpha[2][4], rs[2][4];
    #pragma unroll
    for (int mt = 0; mt < 2; ++mt)
      #pragma unroll
      for (int r = 0; r < 4; ++r) {
        float mn = fmaxf(m_run[mt][r], mt4[mt][r]);
        alpha[mt][r] = __expf(m_run[mt][r] - mn);
        m_run[mt][r] = mn;
        rs[mt][r] = 0.f;
      }
    #pragma unroll
    for (int kf = 0; kf < 4; ++kf)
      #pragma unroll
      for (int mt = 0; mt < 2; ++mt)
        #pragma unroll
        for (int r = 0; r < 4; ++r) {
          float p = __expf(s[mt][kf][r] - m_run[mt][r]);
          s[mt][kf][r] = p;
          rs[mt][r] += p;
        }
    #pragma unroll
    for (int mask = 1; mask < 16; mask <<= 1)
      #pragma unroll
      for (int mt = 0; mt < 2; ++mt)
        #pragma unroll
        for (int r = 0; r < 4; ++r)
          rs[mt][r] += __shfl_xor(rs[mt][r], mask, 64);
    #pragma unroll
    for (int mt = 0; mt < 2; ++mt)
      #pragma unroll
      for (int r = 0; r < 4; ++r)
        l_run[mt][r] = l_run[mt][r] * alpha[mt][r] + rs[mt][r];

    // ---- P -> LDS (warp-private), rescale o ----
    #pragma unroll
    for (int kf = 0; kf < 4; ++kf)
      #pragma unroll
      for (int mt = 0; mt < 2; ++mt)
        #pragma unroll
        for (int r = 0; r < 4; ++r)
          Ps[w][mt * 16 + quad * 4 + r][kf * 16 + ln] = f2bf(s[mt][kf][r]);
    #pragma unroll
    for (int mt = 0; mt < 2; ++mt)
      #pragma unroll
      for (int df = 0; df < 4; ++df)
        #pragma unroll
        for (int r = 0; r < 4; ++r)
          o[mt][df][r] *= alpha[mt][r];

    // ---- P·V (16 MFMA; V-frags shared across mt) ----
    bf16x8 pa[2][2];
    #pragma unroll
    for (int mt = 0; mt < 2; ++mt) {
      pa[mt][0] = *(const bf16x8*)&Ps[w][mt * 16 + ln][quad * 8];
      pa[mt][1] = *(const bf16x8*)&Ps[w][mt * 16 + ln][32 + quad * 8];
    }
    __builtin_amdgcn_s_setprio(1);
    #pragma unroll
    for (int df = 0; df < 4; ++df) {
      int vrow = df * 16 + ln;
      bf16x8 vv0 = *(const bf16x8*)(Vb + vrow * 128 + c0);
      bf16x8 vv1 = *(const bf16x8*)(Vb + vrow * 128 + c1);
      #pragma unroll
      for (int mt = 0; mt < 2; ++mt) {
        o[mt][df] = __builtin_amdgcn_mfma_f32_16x16x32_bf16(pa[mt][0], vv0, o[mt][df], 0, 0, 0);
        o[mt][df] = __builtin_amdgcn_mfma_f32_16x16x32_bf16(pa[mt][1], vv1, o[mt][df], 0, 0, 0);
      }
    }
    __builtin_amdgcn_s_setprio(0);
  }

  // ---- epilogue: o -> Ps (warp-private) -> coalesced 16B stores ----
  float inv[2][4];
  #pragma unroll
  for (int mt = 0; mt < 2; ++mt)
    #pragma unroll
    for (int r = 0; r < 4; ++r) inv[mt][r] = 1.0f / l_run[mt][r];
  #pragma unroll
  for (int mt = 0; mt < 2; ++mt)
    #pragma unroll
    for (int df = 0; df < 4; ++df)
      #pragma unroll
      for (int r = 0; r < 4; ++r)
        Ps[w][mt * 16 + quad * 4 + r][df * 16 + ln] = f2bf(o[mt][df][r] * inv[mt][r]);
  #pragma unroll
  for (int rr = 0; rr < 4; ++rr) {
    int row = rr * 8 + (lane >> 3);
    int col = (lane & 7) * 8;
    u16x8 v = *(const u16x8*)&Ps[w][row][col];
    *(u16x8*)&attn_out[((size_t)b * 1024 + q0 - w * 32 + w * 32 + row + 0) * 768 + h * 64 + col + (size_t)0 * 0] = v;
  }
}

// ---------------- launch ----------------

extern "C" void kernel_launch(void* const* d_in, const int* in_sizes, int n_in,
                              void* d_out, int out_size, void* d_ws, size_t ws_size,
                              hipStream_t stream) {
  const float* x         = (const float*)d_in[0];
  const float* attn_mask = (const float*)d_in[1];
  const float* rel_bias  = (const float*)d_in[2];
  const float* Wq        = (const float*)d_in[3];
  const float* bq        = (const float*)d_in[4];
  const float* Wk        = (const float*)d_in[5];
  const float* bk        = (const float*)d_in[6];
  const float* Wv        = (const float*)d_in[7];
  const float* bv        = (const float*)d_in[8];
  const float* Wo        = (const float*)d_in[9];
  const float* bo        = (const float*)d_in[10];
  const float* Wg        = (const float*)d_in[11];
  const float* bg        = (const float*)d_in[12];
  const float* grep_a    = (const float*)d_in[13];

  char* ws = (char*)d_ws;
  const size_t SZ_XD = (size_t)8192 * 768 * 2;
  const size_t SZ_W  = (size_t)768 * 768 * 2;
  u16*   xb   = (u16*)(ws);
  u16*   wqt  = (u16*)(ws + SZ_XD);
  u16*   wkt  = (u16*)(ws + SZ_XD + SZ_W);
  u16*   wvt  = (u16*)(ws + SZ_XD + 2 * SZ_W);
  u16*   wot  = (u16*)(ws + SZ_XD + 3 * SZ_W);
  u16*   qbuf = (u16*)(ws + SZ_XD + 4 * SZ_W);
  u16*   kbuf = (u16*)(ws + 2 * SZ_XD + 4 * SZ_W);
  u16*   vtbuf= (u16*)(ws + 3 * SZ_XD + 4 * SZ_W);
  u16*   attnb= (u16*)(ws + 4 * SZ_XD + 4 * SZ_W);
  float* ga1f = (float*)(ws + 5 * SZ_XD + 4 * SZ_W);

  cast_gates_kernel<<<6144, 256, 0, stream>>>(x, xb, Wg, bg, grep_a, ga1f);
  transpose_w_kernel<<<dim3(12, 12, 4), 256, 0, stream>>>(Wq, Wk, Wv, Wo, wqt, wkt, wvt, wot);
  gemm_qkv_kernel<<<dim3(6, 64, 3), 256, 0, stream>>>(xb, wqt, wkt, wvt, bq, bk, bv,
                                                      qbuf, kbuf, vtbuf);
  attn_kernel<<<768, 256, 0, stream>>>(qbuf, kbuf, vtbuf, rel_bias, attn_mask, ga1f, attnb);
  gemm_out_kernel<<<dim3(6, 64), 256, 0, stream>>>(attnb, wot, bo, (float*)d_out);
}